// Round 8
// baseline (485.450 us; speedup 1.0000x reference)
//
#include <hip/hip_runtime.h>
#include <cstdint>

// GCGRU cell, restructured:
//   Zg = [x;h] (1536x4000)  -> Z1 = Zg A^T, Z2 = Z1 A^T      (shared by r,u)
//   gates: r,u = sigmoid(W{f,u} . [Zg;Z1;Z2] + b)            (fp32 conv)
//   rh = r*h (1024x4000)    -> Rh1 = rh A^T, Rh2 = Rh1 A^T
//   cand: c = tanh(Wc . [x,rh, Ax,Arh, A2x,A2rh] + bc);  out = u h + (1-u) c
//
// Round-8: discriminating A/B. All prior schedule variants (2ph/4ph, sK2/sK4)
// pin at ~700 TF / MfmaUtil 27% with 1 block/CU. Two candidate causes:
// (a) no cross-block TLP to hide barrier/staging stalls; (b) LDS-read-BW.
// Test: Rh-GEMMs -> round-3 m97 128x128 kernel (16KB LDS, 8 blocks/CU max
// TLP, higher LDS traffic/FLOP, measured 628 TF on Z in round 3); Z-GEMMs
// stay on k_gemm8p (control). sK=2 everywhere (r7: sK4==sK2; halves combine).

#define NREAL 4000
#define NPAD  4096

typedef unsigned short u16;
typedef __attribute__((ext_vector_type(8))) short short8;
typedef __attribute__((ext_vector_type(4))) float f32x4;
typedef __attribute__((ext_vector_type(4))) unsigned short u16x4;
typedef __attribute__((ext_vector_type(8))) unsigned short u16x8;

__device__ __forceinline__ u16 f2bf(float f) {
  unsigned u = __builtin_bit_cast(unsigned, f);
  return (u16)((u + 0x7FFFu + ((u >> 16) & 1u)) >> 16);
}
__device__ __forceinline__ float bf2f(u16 b) {
  unsigned u = ((unsigned)b) << 16;
  return __builtin_bit_cast(float, u);
}

// ---- adj f32 [4000][4000] -> bf16 [4096][4096], zero-padded ----
__global__ __launch_bounds__(256) void k_pack_adj(const float* __restrict__ adj,
                                                  u16* __restrict__ out) {
  const int idx = blockIdx.x * 256 + threadIdx.x;
  const int m = idx >> 10;
  const int n0 = (idx & 1023) << 2;
  u16x4 o;
  if (m < NREAL && n0 < NREAL) {
    const float4 v = *reinterpret_cast<const float4*>(&adj[(long)m * NREAL + n0]);
    o.x = f2bf(v.x); o.y = f2bf(v.y); o.z = f2bf(v.z); o.w = f2bf(v.w);
  } else {
    o.x = 0; o.y = 0; o.z = 0; o.w = 0;
  }
  *reinterpret_cast<u16x4*>(&out[(long)m * NPAD + n0]) = o;
}

// ---- Zg bf16 [1536][4096] = rows (b*96+c): c<32 -> x, else h ----
__global__ __launch_bounds__(256) void k_pack_zg(const float* __restrict__ x,
                                                 const float* __restrict__ h,
                                                 u16* __restrict__ zg) {
  const int idx = blockIdx.x * 256 + threadIdx.x;
  const int row = idx >> 10;
  const int n0 = (idx & 1023) << 2;
  const int b = row / 96, c = row % 96;
  const float* src = (c < 32) ? &x[((long)b * 32 + c) * NREAL]
                              : &h[((long)b * 64 + (c - 32)) * NREAL];
  u16x4 o;
  if (n0 < NREAL) {
    const float4 v = *reinterpret_cast<const float4*>(&src[n0]);
    o.x = f2bf(v.x); o.y = f2bf(v.y); o.z = f2bf(v.z); o.w = f2bf(v.w);
  } else {
    o.x = 0; o.y = 0; o.z = 0; o.w = 0;
  }
  *reinterpret_cast<u16x4*>(&zg[(long)row * NPAD + n0]) = o;
}

// ---- W transpose pack: Wgt[c][128] = [Wf;Wu]^T, Wct[c][64] = Wc^T ----
__global__ __launch_bounds__(256) void k_pack_w(const float* __restrict__ Wf,
                                                const float* __restrict__ Wu,
                                                const float* __restrict__ Wc,
                                                float* __restrict__ Wgt,
                                                float* __restrict__ Wct) {
  const int idx = blockIdx.x * 256 + threadIdx.x;
  if (idx < 288 * 128) {
    const int c = idx >> 7, o = idx & 127;
    Wgt[idx] = (o < 64) ? Wf[o * 288 + c] : Wu[(o - 64) * 288 + c];
  }
  if (idx < 288 * 64) {
    const int c = idx >> 6, o = idx & 63;
    Wct[idx] = Wc[o * 288 + c];
  }
}

#define GLDS(dst, src)                                                         \
  __builtin_amdgcn_global_load_lds(                                            \
      (const __attribute__((address_space(1))) void*)(src),                    \
      (__attribute__((address_space(3))) void*)(dst), 16, 0, 0)

// ---- NT bf16 GEMM, 256x256/BK=64/8-wave, 4-phase dual-barrier skeleton ----
// (control arm; see round-6/7 comments). Writes bf16 at z*chunkElems.
__global__ __launch_bounds__(512) void k_gemm8p(const u16* __restrict__ A,
                                                const u16* __restrict__ B,
                                                u16* __restrict__ Cout,
                                                int ktPerChunk, long chunkElems) {
  __shared__ __align__(16) u16 As[2][256 * 64];
  __shared__ __align__(16) u16 Bs[2][256 * 64];
  const int tid = threadIdx.x;
  const int lane = tid & 63;
  const int wv = tid >> 6;
  const int wm = wv >> 2;           // 0..1  M-half
  const int wn = wv & 3;            // 0..3  N-quarter

  const int srow = tid >> 3;
  const int jlog = (tid & 7) ^ (srow & 7);
  const long kt0 = (long)blockIdx.z * ktPerChunk * 64;
  const u16* aB = A + (long)(blockIdx.y * 256 + srow) * NPAD + kt0 + jlog * 8;
  const u16* bB = B + (long)(blockIdx.x * 256 + srow) * NPAD + kt0 + jlog * 8;
  const int ldst = tid * 8;

  const int fr = lane & 15;
  const int swz = (fr & 7) << 4;
  const int kb0 = (((lane >> 4) << 4)) ^ swz;
  const int kb1 = (64 + ((lane >> 4) << 4)) ^ swz;

  f32x4 acc[8][4] = {};
  const int T = ktPerChunk;

  GLDS(&Bs[0][0 + ldst],     bB);
  GLDS(&Bs[0][4096 + ldst],  bB + 64L * NPAD);
  GLDS(&Bs[0][8192 + ldst],  bB + 128L * NPAD);
  GLDS(&Bs[0][12288 + ldst], bB + 192L * NPAD);
  GLDS(&As[0][0 + ldst],     aB);
  GLDS(&As[0][8192 + ldst],  aB + 128L * NPAD);
  GLDS(&As[0][4096 + ldst],  aB + 64L * NPAD);
  GLDS(&As[0][12288 + ldst], aB + 192L * NPAD);
  asm volatile("s_waitcnt vmcnt(0)" ::: "memory");
  __builtin_amdgcn_s_barrier();

  for (int t = 0; t < T; ++t) {
    const int bs = t & 1;
    const char* Ab = (const char*)&As[bs][0];
    const char* Bb = (const char*)&Bs[bs][0];
    u16* An = &As[bs ^ 1][0];
    u16* Bn = &Bs[bs ^ 1][0];
    const bool more = (t + 1 < T);
    const long ko = (long)(t + 1) * 64;
    short8 bv[4][2];
#pragma unroll
    for (int p = 0; p < 4; ++p) {
      if (p == 0) {
#pragma unroll
        for (int ni = 0; ni < 4; ++ni) {
          const int brow = (wn << 6) + (ni << 4) + fr;
          bv[ni][0] = *(const short8*)(Bb + brow * 128 + kb0);
          bv[ni][1] = *(const short8*)(Bb + brow * 128 + kb1);
        }
      }
      short8 av[2][2];
#pragma unroll
      for (int q = 0; q < 2; ++q) {
        const int arow = (wm << 7) + ((2 * p + q) << 4) + fr;
        av[q][0] = *(const short8*)(Ab + arow * 128 + kb0);
        av[q][1] = *(const short8*)(Ab + arow * 128 + kb1);
      }
      if (more) {
        if (p == 0) { GLDS(Bn + ldst, bB + ko);
                      GLDS(Bn + 4096 + ldst, bB + 64L * NPAD + ko); }
        if (p == 1) { GLDS(Bn + 8192 + ldst, bB + 128L * NPAD + ko);
                      GLDS(Bn + 12288 + ldst, bB + 192L * NPAD + ko); }
        if (p == 2) { GLDS(An + ldst, aB + ko);
                      GLDS(An + 8192 + ldst, aB + 128L * NPAD + ko); }
        if (p == 3) { GLDS(An + 4096 + ldst, aB + 64L * NPAD + ko);
                      GLDS(An + 12288 + ldst, aB + 192L * NPAD + ko); }
      }
      if (p == 0) asm volatile("s_waitcnt lgkmcnt(8)" ::: "memory");
      __builtin_amdgcn_s_barrier();
      asm volatile("s_waitcnt lgkmcnt(0)" ::: "memory");
      __builtin_amdgcn_sched_barrier(0);
      __builtin_amdgcn_s_setprio(1);
#pragma unroll
      for (int q = 0; q < 2; ++q)
#pragma unroll
        for (int ni = 0; ni < 4; ++ni) {
          acc[2 * p + q][ni] = __builtin_amdgcn_mfma_f32_16x16x32_bf16(
              av[q][0], bv[ni][0], acc[2 * p + q][ni], 0, 0, 0);
          acc[2 * p + q][ni] = __builtin_amdgcn_mfma_f32_16x16x32_bf16(
              av[q][1], bv[ni][1], acc[2 * p + q][ni], 0, 0, 0);
        }
      __builtin_amdgcn_s_setprio(0);
      if (p == 1) {
        if (more) asm volatile("s_waitcnt vmcnt(4)" ::: "memory");
        else      asm volatile("s_waitcnt vmcnt(0)" ::: "memory");
      }
      if (p == 3 && more)
        asm volatile("s_waitcnt vmcnt(2)" ::: "memory");
      __builtin_amdgcn_s_barrier();
    }
  }

  u16* C = Cout + (long)blockIdx.z * chunkElems;
  const int rb = blockIdx.y * 256 + (wm << 7) + ((lane >> 4) << 2);
  const int cb = blockIdx.x * 256 + (wn << 6) + fr;
#pragma unroll
  for (int mi = 0; mi < 8; ++mi)
#pragma unroll
    for (int ni = 0; ni < 4; ++ni)
#pragma unroll
      for (int q = 0; q < 4; ++q)
        C[(long)(rb + (mi << 4) + q) * NPAD + cb + (ni << 4)] = f2bf(acc[mi][ni][q]);
}

// ---- m97-structure NT GEMM: 128x128, BK=32, 4 waves, 16KB LDS (max TLP) ----
// Round-3 kernel verbatim (bf16 out + K-chunk offset). 8 blocks/CU possible.
__global__ __launch_bounds__(256) void k_gemm97(const u16* __restrict__ A,
                                                const u16* __restrict__ B,
                                                u16* __restrict__ Cout,
                                                int ktPerChunk, long chunkElems) {
  __shared__ __align__(16) u16 As[128 * 32];
  __shared__ __align__(16) u16 Bs[128 * 32];
  const int tid = threadIdx.x;
  const int wave = tid >> 6;
  const int lane = tid & 63;
  const int bn = blockIdx.x;
  const int bm = blockIdx.y;
  const int ktBegin = blockIdx.z * ktPerChunk;
  const int ktEnd = ktBegin + ktPerChunk;

  const int srow = (wave << 4) + (lane >> 2);
  const int sslot = (lane & 3) << 3;
  const long aRow  = (long)(bm * 128 + srow) * NPAD;
  const long aRow2 = aRow + 64L * NPAD;
  const long bRow  = (long)(bn * 128 + srow) * NPAD;
  const long bRow2 = bRow + 64L * NPAD;
  const int wbase = __builtin_amdgcn_readfirstlane(wave << 9);

  const int wr = (wave >> 1) << 6;
  const int wc = (wave & 1) << 6;
  const int fr = lane & 15;
  const int ks = (lane >> 4) << 3;

  f32x4 acc[4][4] = {};

  for (int kt = ktBegin; kt < ktEnd; ++kt) {
    const long kofs = (long)kt * 32 + sslot;
    __syncthreads();
    GLDS(&As[wbase], A + aRow + kofs);
    GLDS(&As[wbase + 2048], A + aRow2 + kofs);
    GLDS(&Bs[wbase], B + bRow + kofs);
    GLDS(&Bs[wbase + 2048], B + bRow2 + kofs);
    __syncthreads();

    short8 av[4], bv[4];
#pragma unroll
    for (int i = 0; i < 4; ++i) {
      av[i] = *reinterpret_cast<const short8*>(&As[(wr + (i << 4) + fr) * 32 + ks]);
      bv[i] = *reinterpret_cast<const short8*>(&Bs[(wc + (i << 4) + fr) * 32 + ks]);
    }
#pragma unroll
    for (int i = 0; i < 4; ++i)
#pragma unroll
      for (int j = 0; j < 4; ++j)
        acc[i][j] = __builtin_amdgcn_mfma_f32_16x16x32_bf16(av[i], bv[j], acc[i][j], 0, 0, 0);
  }

  u16* C = Cout + (long)blockIdx.z * chunkElems;
  const int rb = bm * 128 + wr + ((lane >> 4) << 2);
  const int cb = bn * 128 + wc + fr;
#pragma unroll
  for (int i = 0; i < 4; ++i)
#pragma unroll
    for (int j = 0; j < 4; ++j)
#pragma unroll
      for (int q = 0; q < 4; ++q)
        C[(long)(rb + (i << 4) + q) * NPAD + cb + (j << 4)] = f2bf(acc[i][j][q]);
}

// ---- sum NC bf16 partial chunks -> bf16 (8 elems/thread) ----
template<int NC>
__global__ __launch_bounds__(256) void k_combine_bf(const u16* __restrict__ P,
                                                    long chunkElems,
                                                    u16* __restrict__ out) {
  const long i8 = ((long)blockIdx.x * 256 + threadIdx.x) * 8;
  float s[8];
  {
    const u16x8 v = *reinterpret_cast<const u16x8*>(&P[i8]);
#pragma unroll
    for (int j = 0; j < 8; ++j) s[j] = bf2f(v[j]);
  }
#pragma unroll
  for (int c = 1; c < NC; ++c) {
    const u16x8 v = *reinterpret_cast<const u16x8*>(&P[(long)c * chunkElems + i8]);
#pragma unroll
    for (int j = 0; j < 8; ++j) s[j] += bf2f(v[j]);
  }
  u16x8 o;
#pragma unroll
  for (int j = 0; j < 8; ++j) o[j] = f2bf(s[j]);
  *reinterpret_cast<u16x8*>(&out[i8]) = o;
}

// ---- gates: r,u = sigmoid(Wgt^T.[z;z1;z2]+b); emit rh(bf16 [+f32]), u(f32) ----
__global__ __launch_bounds__(512) void k_gates(
    const float* __restrict__ x, const float* __restrict__ h,
    const float* __restrict__ Wgt,
    const float* __restrict__ bfv, const float* __restrict__ buv,
    const u16* __restrict__ Z1, const u16* __restrict__ Z2,
    u16* __restrict__ rh_bf, float* __restrict__ rh_f, float* __restrict__ u_f) {
  const int lane = threadIdx.x & 63;
  const int wq = __builtin_amdgcn_readfirstlane(threadIdx.x >> 6);
  const int b = blockIdx.y;
  const int n0 = blockIdx.x * 128 + (lane << 1);
  if (n0 >= NREAL) return;
  const int ob = wq << 4;
  const float* xb = x + (long)b * 32 * NREAL + n0;
  const float* hb = h + (long)b * 64 * NREAL + n0;
  const u16* z1b = Z1 + (long)b * 96 * NPAD + n0;
  const u16* z2b = Z2 + (long)b * 96 * NPAD + n0;

  float a0[16] = {}, a1[16] = {};
#pragma unroll 4
  for (int c = 0; c < 32; ++c) {
    const float2 f = *reinterpret_cast<const float2*>(&xb[(long)c * NREAL]);
#pragma unroll
    for (int oi = 0; oi < 16; ++oi) {
      const float w = Wgt[c * 128 + ob + oi];
      a0[oi] = fmaf(w, f.x, a0[oi]); a1[oi] = fmaf(w, f.y, a1[oi]);
    }
  }
#pragma unroll 4
  for (int c = 0; c < 64; ++c) {
    const float2 f = *reinterpret_cast<const float2*>(&hb[(long)c * NREAL]);
#pragma unroll
    for (int oi = 0; oi < 16; ++oi) {
      const float w = Wgt[(32 + c) * 128 + ob + oi];
      a0[oi] = fmaf(w, f.x, a0[oi]); a1[oi] = fmaf(w, f.y, a1[oi]);
    }
  }
#pragma unroll 4
  for (int c = 0; c < 96; ++c) {
    const unsigned pv = *reinterpret_cast<const unsigned*>(&z1b[(long)c * NPAD]);
    const float f0 = bf2f((u16)(pv & 0xffff)), f1 = bf2f((u16)(pv >> 16));
#pragma unroll
    for (int oi = 0; oi < 16; ++oi) {
      const float w = Wgt[(96 + c) * 128 + ob + oi];
      a0[oi] = fmaf(w, f0, a0[oi]); a1[oi] = fmaf(w, f1, a1[oi]);
    }
  }
#pragma unroll 4
  for (int c = 0; c < 96; ++c) {
    const unsigned pv = *reinterpret_cast<const unsigned*>(&z2b[(long)c * NPAD]);
    const float f0 = bf2f((u16)(pv & 0xffff)), f1 = bf2f((u16)(pv >> 16));
#pragma unroll
    for (int oi = 0; oi < 16; ++oi) {
      const float w = Wgt[(192 + c) * 128 + ob + oi];
      a0[oi] = fmaf(w, f0, a0[oi]); a1[oi] = fmaf(w, f1, a1[oi]);
    }
  }

  if (wq < 4) {
#pragma unroll
    for (int oi = 0; oi < 16; ++oi) {
      const int og = ob + oi;
      const float bb = bfv[og];
      const float r0 = 1.f / (1.f + __expf(-(a0[oi] + bb)));
      const float r1 = 1.f / (1.f + __expf(-(a1[oi] + bb)));
      const float2 hv = *reinterpret_cast<const float2*>(&hb[(long)og * NREAL]);
      const float rh0 = r0 * hv.x, rh1 = r1 * hv.y;
      if (rh_f)
        *reinterpret_cast<float2*>(&rh_f[((long)b * 64 + og) * NREAL + n0]) =
            make_float2(rh0, rh1);
      const unsigned pk = (unsigned)f2bf(rh0) | ((unsigned)f2bf(rh1) << 16);
      *reinterpret_cast<unsigned*>(&rh_bf[((long)b * 64 + og) * NPAD + n0]) = pk;
    }
  } else {
#pragma unroll
    for (int oi = 0; oi < 16; ++oi) {
      const int og = (ob - 64) + oi;
      const float bb = buv[og];
      const float u0 = 1.f / (1.f + __expf(-(a0[oi] + bb)));
      const float u1 = 1.f / (1.f + __expf(-(a1[oi] + bb)));
      *reinterpret_cast<float2*>(&u_f[((long)b * 64 + og) * NREAL + n0]) =
          make_float2(u0, u1);
    }
  }
}

// ---- candidate + output ----
template<bool RHF32>
__global__ __launch_bounds__(512) void k_cand(
    const float* __restrict__ x, const float* __restrict__ h,
    const float* __restrict__ Wct, const float* __restrict__ bcv,
    const u16* __restrict__ Z1, const u16* __restrict__ Z2,
    const u16* __restrict__ Rhb, const u16* __restrict__ Rh1,
    const u16* __restrict__ Rh2,
    const float* __restrict__ rh_f, const float* __restrict__ u_f,
    float* __restrict__ out) {
  const int lane = threadIdx.x & 63;
  const int wq = __builtin_amdgcn_readfirstlane(threadIdx.x >> 6);
  const int ob = (wq & 3) << 4;
  const int n = blockIdx.x * 128 + ((wq >> 2) << 6) + lane;
  const int b = blockIdx.y;
  if (n >= NREAL) return;
  const float* xb = x + (long)b * 32 * NREAL + n;
  const float* hb = h + (long)b * 64 * NREAL + n;
  const u16* z1b = Z1 + (long)b * 96 * NPAD + n;
  const u16* z2b = Z2 + (long)b * 96 * NPAD + n;
  const u16* r1b = Rh1 + (long)b * 64 * NPAD + n;
  const u16* r2b = Rh2 + (long)b * 64 * NPAD + n;
  const float* rfb = rh_f + (long)b * 64 * NREAL + n;
  const u16* rbb = Rhb + (long)b * 64 * NPAD + n;

  float acc[16] = {};
#pragma unroll 4
  for (int c = 0; c < 32; ++c) {
    const float f = xb[(long)c * NREAL];
#pragma unroll
    for (int oi = 0; oi < 16; ++oi)
      acc[oi] = fmaf(Wct[c * 64 + ob + oi], f, acc[oi]);
  }
#pragma unroll 4
  for (int c = 0; c < 64; ++c) {
    const float f = RHF32 ? rfb[(long)c * NREAL] : bf2f(rbb[(long)c * NPAD]);
#pragma unroll
    for (int oi = 0; oi < 16; ++oi)
      acc[oi] = fmaf(Wct[(32 + c) * 64 + ob + oi], f, acc[oi]);
  }
#pragma unroll 4
  for (int c = 0; c < 32; ++c) {
    const float f = bf2f(z1b[(long)c * NPAD]);
#pragma unroll
    for (int oi = 0; oi < 16; ++oi)
      acc[oi] = fmaf(Wct[(96 + c) * 64 + ob + oi], f, acc[oi]);
  }
#pragma unroll 4
  for (int c = 0; c < 64; ++c) {
    const float f = bf2f(r1b[(long)c * NPAD]);
#pragma unroll
    for (int oi = 0; oi < 16; ++oi)
      acc[oi] = fmaf(Wct[(128 + c) * 64 + ob + oi], f, acc[oi]);
  }
#pragma unroll 4
  for (int c = 0; c < 32; ++c) {
    const float f = bf2f(z2b[(long)c * NPAD]);
#pragma unroll
    for (int oi = 0; oi < 16; ++oi)
      acc[oi] = fmaf(Wct[(192 + c) * 64 + ob + oi], f, acc[oi]);
  }
#pragma unroll 4
  for (int c = 0; c < 64; ++c) {
    const float f = bf2f(r2b[(long)c * NPAD]);
#pragma unroll
    for (int oi = 0; oi < 16; ++oi)
      acc[oi] = fmaf(Wct[(224 + c) * 64 + ob + oi], f, acc[oi]);
  }

#pragma unroll
  for (int oi = 0; oi < 16; ++oi) {
    const int og = ob + oi;
    float v = acc[oi] + bcv[og];
    v = fminf(fmaxf(v, -15.f), 15.f);
    const float e2 = __expf(2.f * v);
    const float cv = (e2 - 1.f) / (e2 + 1.f);
    const float u = u_f[((long)b * 64 + og) * NREAL + n];
    out[((long)b * 64 + og) * NREAL + n] = u * hb[(long)og * NREAL] + (1.f - u) * cv;
  }
}

extern "C" void kernel_launch(void* const* d_in, const int* in_sizes, int n_in,
                              void* d_out, int out_size, void* d_ws, size_t ws_size,
                              hipStream_t stream) {
  const float* x   = (const float*)d_in[0];
  const float* h   = (const float*)d_in[1];
  const float* adj = (const float*)d_in[2];
  const float* Wf  = (const float*)d_in[3];
  const float* bf_ = (const float*)d_in[4];
  const float* Wu  = (const float*)d_in[5];
  const float* bu_ = (const float*)d_in[6];
  const float* Wc  = (const float*)d_in[7];
  const float* bc_ = (const float*)d_in[8];
  float* out = (float*)d_out;

  char* p = (char*)d_ws;
  auto alloc = [&](size_t bytes) { char* r = p; p += bytes; return r; };
  u16* adjb = (u16*)alloc((size_t)NPAD * NPAD * 2);
  u16* Zg   = (u16*)alloc((size_t)1536 * NPAD * 2);       // Rhb aliases Zg
  u16* Rhb  = Zg;
  u16* Z1   = (u16*)alloc((size_t)1536 * NPAD * 2);
  u16* Z2   = (u16*)alloc((size_t)1536 * NPAD * 2);
  u16* Rh1  = (u16*)alloc((size_t)1024 * NPAD * 2);
  u16* Rh2  = (u16*)alloc((size_t)1024 * NPAD * 2);
  float* uf = (float*)alloc((size_t)16 * 64 * NREAL * 4);
  float* Wgt = (float*)alloc(288 * 128 * 4);
  float* Wct = (float*)alloc(288 * 64 * 4);
  const size_t RHFB = (size_t)16 * 64 * NREAL * 4;
  size_t used = (size_t)(p - (char*)d_ws);
  float* rhf = nullptr;
  if (ws_size >= used + RHFB) rhf = (float*)alloc(RHFB);
  used = (size_t)(p - (char*)d_ws);

  // split-K bf16 partial buffer: 2 chunks of the largest output (Z: 12.58MB)
  const size_t PB2 = (size_t)2 * 1536 * NPAD * 2;   // 25.17 MB
  int sK = 1;
  u16* Pb = nullptr;
  if (ws_size >= used + PB2) { sK = 2; Pb = (u16*)alloc(PB2); }

  // Z-GEMMs (M=1536): 256^2 8-phase kernel (control arm)
  auto gemmZ = [&](const u16* Ax, const u16* Bx, u16* Cb) {
    const long ce = (long)1536 * NPAD;
    if (sK == 2) {
      k_gemm8p<<<dim3(16, 6, 2), 512, 0, stream>>>(Ax, Bx, Pb, 32, ce);
      k_combine_bf<2><<<dim3((int)(ce / 2048)), 256, 0, stream>>>(Pb, ce, Cb);
    } else {
      k_gemm8p<<<dim3(16, 6, 1), 512, 0, stream>>>(Ax, Bx, Cb, 64, ce);
    }
  };
  // Rh-GEMMs (M=1024): m97 128^2 kernel (TLP arm; 512 blocks all-resident)
  auto gemmR = [&](const u16* Ax, const u16* Bx, u16* Cb) {
    const long ce = (long)1024 * NPAD;
    if (sK == 2) {
      k_gemm97<<<dim3(32, 8, 2), 256, 0, stream>>>(Ax, Bx, Pb, 64, ce);
      k_combine_bf<2><<<dim3((int)(ce / 2048)), 256, 0, stream>>>(Pb, ce, Cb);
    } else {
      k_gemm97<<<dim3(32, 8, 1), 256, 0, stream>>>(Ax, Bx, Cb, 128, ce);
    }
  };

  k_pack_adj<<<dim3(NPAD * (NPAD / 4) / 256), 256, 0, stream>>>(adj, adjb);
  k_pack_zg <<<dim3(1536 * (NPAD / 4) / 256), 256, 0, stream>>>(x, h, Zg);
  k_pack_w  <<<dim3(144), 256, 0, stream>>>(Wf, Wu, Wc, Wgt, Wct);
  gemmZ(Zg, adjb, Z1);                                        // Z1 = Zg A^T
  gemmZ(Z1, adjb, Z2);                                        // Z2 = Z1 A^T
  k_gates<<<dim3(32, 16), 512, 0, stream>>>(x, h, Wgt, bf_, bu_, Z1, Z2,
                                            Rhb, rhf, uf);
  gemmR(Rhb, adjb, Rh1);                                      // Rh1 = rh A^T
  gemmR(Rh1, adjb, Rh2);                                      // Rh2 = Rh1 A^T
  if (rhf)
    k_cand<true><<<dim3(32, 16), 512, 0, stream>>>(x, h, Wct, bc_, Z1, Z2, Rhb,
                                                   Rh1, Rh2, rhf, uf, out);
  else
    k_cand<false><<<dim3(32, 16), 512, 0, stream>>>(x, h, Wct, bc_, Z1, Z2, Rhb,
                                                    Rh1, Rh2, rhf, uf, out);
}